// Round 1
// baseline (114.702 us; speedup 1.0000x reference)
//
#include <hip/hip_runtime.h>
#include <math.h>

#define BB 16
#define CC 80
#define HH 128
#define WW 128
#define HW (HH*WW)
#define N1 (CC*HW)          // 1,310,720 elements per batch per map
#define KK 128
#define FEPS 1e-4f
#define FBLOCKS 128         // blocks per (batch, map) in focal kernel

// ws layout (floats):
// [m*48 + 0  + b]  pos_loss  (m=0 tl, m=1 br)
// [m*48 + 16 + b]  neg_loss
// [m*48 + 32 + b]  n (pos count)
// [96] off_sum_tl  [97] off_sum_br  [98] mask_sum  [99] pull  [100] push

__global__ __launch_bounds__(256) void focal_kernel(
    const float* __restrict__ t_tl, const float* __restrict__ t_br,
    const float* __restrict__ x_tl, const float* __restrict__ x_br,
    float* __restrict__ ws)
{
    const int m = blockIdx.z;
    const int b = blockIdx.y;
    const float* __restrict__ t = (m ? t_br : t_tl) + (size_t)b * N1;
    const float* __restrict__ x = (m ? x_br : x_tl) + (size_t)b * N1;
    const int NF4   = N1 / 4;            // 327680
    const int chunk = NF4 / FBLOCKS;     // 2560
    const int base  = blockIdx.x * chunk;

    float accp = 0.0f, accn = 0.0f, cnt = 0.0f;
    for (int i = threadIdx.x; i < chunk; i += 256) {
        float4 tv = ((const float4*)t)[base + i];
        float4 xv = ((const float4*)x)[base + i];
        #pragma unroll
        for (int c = 0; c < 4; ++c) {
            float tt = (&tv.x)[c];
            float xx = (&xv.x)[c];
            float e  = __expf(-xx);
            float L  = __logf(1.0f + e);     // log(1+e^-x)
            float p  = 1.0f / (1.0f + e);    // sigmoid(x)
            float logp   = -L;               // log(p)
            float log1mp = -xx - L;          // log(1-p)
            float om = 1.0f - p;
            float u  = 1.0f - tt;
            float u2 = u * u;
            bool pos = (tt == 1.0f);
            float pv = om * om * logp;
            float nv = u2 * u2 * p * p * log1mp;
            accp += pos ? pv : 0.0f;
            accn += pos ? 0.0f : nv;         // neg: t < 1  (t <= 1 always)
            cnt  += pos ? 1.0f : 0.0f;
        }
    }

    // block reduce 3 values: wave shuffle then LDS across 4 waves
    #pragma unroll
    for (int off = 32; off > 0; off >>= 1) {
        accp += __shfl_down(accp, off, 64);
        accn += __shfl_down(accn, off, 64);
        cnt  += __shfl_down(cnt , off, 64);
    }
    __shared__ float red[3][4];
    const int lane = threadIdx.x & 63, wv = threadIdx.x >> 6;
    if (lane == 0) { red[0][wv] = accp; red[1][wv] = accn; red[2][wv] = cnt; }
    __syncthreads();
    if (threadIdx.x == 0) {
        float P = red[0][0] + red[0][1] + red[0][2] + red[0][3];
        float Nn = red[1][0] + red[1][1] + red[1][2] + red[1][3];
        float Cn = red[2][0] + red[2][1] + red[2][2] + red[2][3];
        atomicAdd(&ws[m*48 +  0 + b], P);
        atomicAdd(&ws[m*48 + 16 + b], Nn);
        atomicAdd(&ws[m*48 + 32 + b], Cn);
    }
}

__global__ void off_kernel(
    const float* __restrict__ to_tl, const float* __restrict__ to_br,
    const float* __restrict__ po_tl, const float* __restrict__ po_br,
    const int* __restrict__ idx_tl, const int* __restrict__ idx_br,
    const int* __restrict__ mask, float* __restrict__ ws)
{
    const int b = blockIdx.x, k = threadIdx.x;   // block = KK threads
    float mf = (float)mask[b*KK + k];
    const int itl = idx_tl[b*KK + k];
    const int ibr = idx_br[b*KK + k];
    float s_tl = 0.0f, s_br = 0.0f;
    #pragma unroll
    for (int ch = 0; ch < 2; ++ch) {
        float pv = po_tl[((size_t)b*2 + ch)*HW + itl];
        float tv = to_tl[(b*KK + k)*2 + ch];
        float d = pv - tv, ad = fabsf(d);
        s_tl += (ad < 1.0f) ? 0.5f*d*d : (ad - 0.5f);
        pv = po_br[((size_t)b*2 + ch)*HW + ibr];
        tv = to_br[(b*KK + k)*2 + ch];
        d = pv - tv; ad = fabsf(d);
        s_br += (ad < 1.0f) ? 0.5f*d*d : (ad - 0.5f);
    }
    s_tl *= mf; s_br *= mf;

    #pragma unroll
    for (int off = 32; off > 0; off >>= 1) {
        s_tl += __shfl_down(s_tl, off, 64);
        s_br += __shfl_down(s_br, off, 64);
        mf   += __shfl_down(mf  , off, 64);
    }
    __shared__ float r[3][2];
    const int lane = threadIdx.x & 63, wv = threadIdx.x >> 6;
    if (lane == 0) { r[0][wv] = s_tl; r[1][wv] = s_br; r[2][wv] = mf; }
    __syncthreads();
    if (threadIdx.x == 0) {
        atomicAdd(&ws[96], r[0][0] + r[0][1]);
        atomicAdd(&ws[97], r[1][0] + r[1][1]);
        atomicAdd(&ws[98], r[2][0] + r[2][1]);
    }
}

__global__ void trip_kernel(
    const float* __restrict__ e_tl, const float* __restrict__ e_br,
    const int* __restrict__ idx_tl, const int* __restrict__ idx_br,
    const int* __restrict__ mask, float* __restrict__ ws)
{
    const int b = blockIdx.x, k = threadIdx.x;   // block = KK threads
    __shared__ float ek_s[KK], mf_s[KK];
    __shared__ float nred[2];

    float mf = (float)mask[b*KK + k];
    float tl = e_tl[(size_t)b*HW + idx_tl[b*KK + k]];
    float br = e_br[(size_t)b*HW + idx_br[b*KK + k]];
    float ek = 0.5f * (tl + br);
    ek_s[k] = ek; mf_s[k] = mf;

    float nm = mf;
    #pragma unroll
    for (int off = 32; off > 0; off >>= 1) nm += __shfl_down(nm, off, 64);
    if ((threadIdx.x & 63) == 0) nred[threadIdx.x >> 6] = nm;
    __syncthreads();
    const float num  = nred[0] + nred[1];
    const float inv  = 1.0f / (num + FEPS);
    const float num2 = (num - 1.0f) * num;
    const float inv2 = 1.0f / (num2 + FEPS);

    float pull = ((tl-ek)*(tl-ek) + (br-ek)*(br-ek)) * inv * mf;

    float push = 0.0f;
    if (mf == 1.0f) {
        for (int j = 0; j < KK; ++j) {
            if (mf_s[j] == 1.0f) {
                float d = fabsf(ek_s[j] - ek);
                float term = fmaxf(2.0f - d, 0.0f) - 2.0f * inv;
                push += term * inv2;
            }
        }
    }

    #pragma unroll
    for (int off = 32; off > 0; off >>= 1) {
        pull += __shfl_down(pull, off, 64);
        push += __shfl_down(push, off, 64);
    }
    __shared__ float r[2][2];
    const int lane = threadIdx.x & 63, wv = threadIdx.x >> 6;
    if (lane == 0) { r[0][wv] = pull; r[1][wv] = push; }
    __syncthreads();
    if (threadIdx.x == 0) {
        atomicAdd(&ws[99],  r[0][0] + r[0][1]);
        atomicAdd(&ws[100], r[1][0] + r[1][1]);
    }
}

__global__ void fin_kernel(const float* __restrict__ ws, float* __restrict__ out)
{
    if (threadIdx.x == 0 && blockIdx.x == 0) {
        float det = 0.0f;
        for (int m = 0; m < 2; ++m) {
            float f = 0.0f;
            for (int b = 0; b < BB; ++b) {
                float pos = ws[m*48 +  0 + b];
                float neg = ws[m*48 + 16 + b];
                float n   = ws[m*48 + 32 + b];
                float per = (n == 0.0f) ? neg : (pos + neg) / n;
                f -= per;                        // focal = -sum(per)
            }
            det += 0.5f * f;
        }
        float numoff = ws[98] * 2.0f;
        float off = ws[96] / (numoff + FEPS) + ws[97] / (numoff + FEPS);
        out[0] = (det + ws[99] + ws[100] + off) / (float)BB;
    }
}

extern "C" void kernel_launch(void* const* d_in, const int* in_sizes, int n_in,
                              void* d_out, int out_size, void* d_ws, size_t ws_size,
                              hipStream_t stream) {
    const float* t_tl  = (const float*)d_in[0];
    const float* t_br  = (const float*)d_in[1];
    const float* to_tl = (const float*)d_in[2];
    const float* to_br = (const float*)d_in[3];
    const float* x_tl  = (const float*)d_in[4];
    const float* x_br  = (const float*)d_in[5];
    const float* po_tl = (const float*)d_in[6];
    const float* po_br = (const float*)d_in[7];
    const float* e_tl  = (const float*)d_in[8];
    const float* e_br  = (const float*)d_in[9];
    const int* idx_tl  = (const int*)d_in[10];
    const int* idx_br  = (const int*)d_in[11];
    const int* mask    = (const int*)d_in[12];
    float* ws = (float*)d_ws;

    hipMemsetAsync(ws, 0, 512, stream);
    focal_kernel<<<dim3(FBLOCKS, BB, 2), 256, 0, stream>>>(t_tl, t_br, x_tl, x_br, ws);
    off_kernel  <<<BB, KK, 0, stream>>>(to_tl, to_br, po_tl, po_br, idx_tl, idx_br, mask, ws);
    trip_kernel <<<BB, KK, 0, stream>>>(e_tl, e_br, idx_tl, idx_br, mask, ws);
    fin_kernel  <<<1, 64, 0, stream>>>(ws, (float*)d_out);
}

// Round 2
// 106.069 us; speedup vs baseline: 1.0814x; 1.0814x over previous
//
#include <hip/hip_runtime.h>
#include <math.h>

#define BB 16
#define CC 80
#define HH 128
#define WW 128
#define HW (HH*WW)
#define N1 (CC*HW)          // 1,310,720 elements per batch per map
#define KK 128
#define FEPS 1e-4f
#define FBLOCKS 128         // blocks per (batch, map) in focal kernel
#define CHUNK4 2560         // float4s per block (N1/4/FBLOCKS)

// ws layout (floats):
// [m*48 + 0  + b]  A  (pos_loss / -ln2)
// [m*48 + 16 + b]  B  (neg_loss / -ln2)
// [m*48 + 32 + b]  n  (pos count)
// [96] off_sum_tl  [97] off_sum_br  [98] mask_sum  [99] pull  [100] push

__device__ __forceinline__ void proc(float tt, float xx,
                                     float& A, float& B, float& cnt)
{
    const float NLOG2E = -1.4426950408889634f;
    float z  = xx * NLOG2E;                 // -x*log2(e)
    float e  = exp2f(z);                    // e^-x          (v_exp_f32)
    float s  = 1.0f + e;
    float L  = __log2f(s);                  // log2(1+e^-x)  (v_log_f32)
    float p  = __builtin_amdgcn_rcpf(s);    // sigmoid(x)    (v_rcp_f32)
    float ep = e * p;                       // 1-p
    float a  = ep * ep * L;                 // (1-p)^2 * log2(1/p)
    float u  = 1.0f - tt;
    float u2 = u * u;
    float pw = p * u2;                      // p*(1-t)^2
    float bv = pw * pw * (L - z);           // (1-t)^4 p^2 log2(1/(1-p)); ==0 at t==1
    B += bv;
    bool pos = (tt == 1.0f);
    A   += pos ? a : 0.0f;
    cnt += pos ? 1.0f : 0.0f;
}

__global__ __launch_bounds__(256) void focal_kernel(
    const float* __restrict__ t_tl, const float* __restrict__ t_br,
    const float* __restrict__ x_tl, const float* __restrict__ x_br,
    float* __restrict__ ws)
{
    const int m = blockIdx.z;
    const int b = blockIdx.y;
    const float* __restrict__ t = (m ? t_br : t_tl) + (size_t)b * N1;
    const float* __restrict__ x = (m ? x_br : x_tl) + (size_t)b * N1;
    const int base = blockIdx.x * CHUNK4;
    const float4* __restrict__ T4 = (const float4*)t + base;
    const float4* __restrict__ X4 = (const float4*)x + base;

    float A = 0.0f, B = 0.0f, cnt = 0.0f;
    #pragma unroll
    for (int it = 0; it < 5; ++it) {
        const int i = threadIdx.x + it * 512;
        float4 tv0 = T4[i];
        float4 xv0 = X4[i];
        float4 tv1 = T4[i + 256];
        float4 xv1 = X4[i + 256];
        #pragma unroll
        for (int c = 0; c < 4; ++c) proc((&tv0.x)[c], (&xv0.x)[c], A, B, cnt);
        #pragma unroll
        for (int c = 0; c < 4; ++c) proc((&tv1.x)[c], (&xv1.x)[c], A, B, cnt);
    }

    #pragma unroll
    for (int off = 32; off > 0; off >>= 1) {
        A   += __shfl_down(A  , off, 64);
        B   += __shfl_down(B  , off, 64);
        cnt += __shfl_down(cnt, off, 64);
    }
    __shared__ float red[3][4];
    const int lane = threadIdx.x & 63, wv = threadIdx.x >> 6;
    if (lane == 0) { red[0][wv] = A; red[1][wv] = B; red[2][wv] = cnt; }
    __syncthreads();
    if (threadIdx.x == 0) {
        atomicAdd(&ws[m*48 +  0 + b], red[0][0] + red[0][1] + red[0][2] + red[0][3]);
        atomicAdd(&ws[m*48 + 16 + b], red[1][0] + red[1][1] + red[1][2] + red[1][3]);
        atomicAdd(&ws[m*48 + 32 + b], red[2][0] + red[2][1] + red[2][2] + red[2][3]);
    }
}

// off-loss + triplet fused: one block per batch, KK=128 threads (2 waves)
__global__ void small_kernel(
    const float* __restrict__ to_tl, const float* __restrict__ to_br,
    const float* __restrict__ po_tl, const float* __restrict__ po_br,
    const float* __restrict__ e_tl,  const float* __restrict__ e_br,
    const int* __restrict__ idx_tl,  const int* __restrict__ idx_br,
    const int* __restrict__ mask,    float* __restrict__ ws)
{
    const int b = blockIdx.x, k = threadIdx.x;
    const int lane = threadIdx.x & 63, wv = threadIdx.x >> 6;

    float mf = (float)mask[b*KK + k];
    const int itl = idx_tl[b*KK + k];
    const int ibr = idx_br[b*KK + k];

    // ---- offset loss partials ----
    float s_tl = 0.0f, s_br = 0.0f;
    #pragma unroll
    for (int ch = 0; ch < 2; ++ch) {
        float pv = po_tl[((size_t)b*2 + ch)*HW + itl];
        float tv = to_tl[(b*KK + k)*2 + ch];
        float d = pv - tv, ad = fabsf(d);
        s_tl += (ad < 1.0f) ? 0.5f*d*d : (ad - 0.5f);
        pv = po_br[((size_t)b*2 + ch)*HW + ibr];
        tv = to_br[(b*KK + k)*2 + ch];
        d = pv - tv; ad = fabsf(d);
        s_br += (ad < 1.0f) ? 0.5f*d*d : (ad - 0.5f);
    }
    s_tl *= mf; s_br *= mf;

    // ---- triplet setup ----
    __shared__ float ek_s[KK], mf_s[KK], nred[2];
    float tl = e_tl[(size_t)b*HW + itl];
    float br = e_br[(size_t)b*HW + ibr];
    float ek = 0.5f * (tl + br);
    ek_s[k] = ek; mf_s[k] = mf;

    float nm = mf;
    #pragma unroll
    for (int off = 32; off > 0; off >>= 1) nm += __shfl_down(nm, off, 64);
    if (lane == 0) nred[wv] = nm;
    __syncthreads();
    const float num  = nred[0] + nred[1];
    const float inv  = 1.0f / (num + FEPS);
    const float num2 = (num - 1.0f) * num;
    const float inv2 = 1.0f / (num2 + FEPS);

    float pull = ((tl-ek)*(tl-ek) + (br-ek)*(br-ek)) * inv * mf;

    float push = 0.0f;
    if (mf == 1.0f) {
        for (int j = 0; j < KK; ++j) {
            if (mf_s[j] == 1.0f) {
                float d = fabsf(ek_s[j] - ek);
                push += (fmaxf(2.0f - d, 0.0f) - 2.0f * inv) * inv2;
            }
        }
    }

    #pragma unroll
    for (int off = 32; off > 0; off >>= 1) {
        s_tl += __shfl_down(s_tl, off, 64);
        s_br += __shfl_down(s_br, off, 64);
        mf   += __shfl_down(mf  , off, 64);
        pull += __shfl_down(pull, off, 64);
        push += __shfl_down(push, off, 64);
    }
    __shared__ float r[5][2];
    if (lane == 0) {
        r[0][wv] = s_tl; r[1][wv] = s_br; r[2][wv] = mf;
        r[3][wv] = pull; r[4][wv] = push;
    }
    __syncthreads();
    if (threadIdx.x == 0) {
        atomicAdd(&ws[96],  r[0][0] + r[0][1]);
        atomicAdd(&ws[97],  r[1][0] + r[1][1]);
        atomicAdd(&ws[98],  r[2][0] + r[2][1]);
        atomicAdd(&ws[99],  r[3][0] + r[3][1]);
        atomicAdd(&ws[100], r[4][0] + r[4][1]);
    }
}

__global__ void fin_kernel(const float* __restrict__ ws, float* __restrict__ out)
{
    if (threadIdx.x == 0 && blockIdx.x == 0) {
        const float NLN2 = -0.6931471805599453f;
        float det = 0.0f;
        for (int m = 0; m < 2; ++m) {
            float f = 0.0f;
            for (int b = 0; b < BB; ++b) {
                float pos = NLN2 * ws[m*48 +  0 + b];
                float neg = NLN2 * ws[m*48 + 16 + b];
                float n   = ws[m*48 + 32 + b];
                float per = (n == 0.0f) ? neg : (pos + neg) / n;
                f -= per;
            }
            det += 0.5f * f;
        }
        float numoff = ws[98] * 2.0f;
        float off = ws[96] / (numoff + FEPS) + ws[97] / (numoff + FEPS);
        out[0] = (det + ws[99] + ws[100] + off) / (float)BB;
    }
}

extern "C" void kernel_launch(void* const* d_in, const int* in_sizes, int n_in,
                              void* d_out, int out_size, void* d_ws, size_t ws_size,
                              hipStream_t stream) {
    const float* t_tl  = (const float*)d_in[0];
    const float* t_br  = (const float*)d_in[1];
    const float* to_tl = (const float*)d_in[2];
    const float* to_br = (const float*)d_in[3];
    const float* x_tl  = (const float*)d_in[4];
    const float* x_br  = (const float*)d_in[5];
    const float* po_tl = (const float*)d_in[6];
    const float* po_br = (const float*)d_in[7];
    const float* e_tl  = (const float*)d_in[8];
    const float* e_br  = (const float*)d_in[9];
    const int* idx_tl  = (const int*)d_in[10];
    const int* idx_br  = (const int*)d_in[11];
    const int* mask    = (const int*)d_in[12];
    float* ws = (float*)d_ws;

    hipMemsetAsync(ws, 0, 512, stream);
    focal_kernel<<<dim3(FBLOCKS, BB, 2), 256, 0, stream>>>(t_tl, t_br, x_tl, x_br, ws);
    small_kernel<<<BB, KK, 0, stream>>>(to_tl, to_br, po_tl, po_br, e_tl, e_br,
                                        idx_tl, idx_br, mask, ws);
    fin_kernel  <<<1, 64, 0, stream>>>(ws, (float*)d_out);
}

// Round 3
// 88.798 us; speedup vs baseline: 1.2917x; 1.1945x over previous
//
#include <hip/hip_runtime.h>
#include <math.h>

#define BB 16
#define CC 80
#define HH 128
#define WW 128
#define HW (HH*WW)
#define N1 (CC*HW)          // 1,310,720 elements per batch per map
#define KK 128
#define FEPS 1e-4f
#define FB2 64              // blocks per (batch, map) in focal kernel
#define NJ 10               // j-iterations; per thread 2 float4/array/iter

// ws layout (floats):
// [m*48 + 0  + b]  A  (pos_loss / -ln2)
// [m*48 + 16 + b]  B  (neg_loss / -ln2)
// [m*48 + 32 + b]  n  (pos count)
// [96] off_sum_tl  [97] off_sum_br  [98] mask_sum  [99] pull  [100] push

__device__ __forceinline__ void proc(float tt, float xx,
                                     float& A, float& B, float& cnt)
{
    const float NLOG2E = -1.4426950408889634f;
    float z  = xx * NLOG2E;                 // -x*log2(e)
    float e  = exp2f(z);                    // e^-x          (v_exp_f32)
    float s  = 1.0f + e;
    float L  = __log2f(s);                  // log2(1+e^-x)  (v_log_f32)
    float p  = __builtin_amdgcn_rcpf(s);    // sigmoid(x)    (v_rcp_f32)
    float ep = e * p;                       // 1-p
    float a  = ep * ep * L;                 // (1-p)^2 * log2(1/p)
    float u  = 1.0f - tt;
    float u2 = u * u;
    float pw = p * u2;                      // p*(1-t)^2
    float bv = pw * pw * (L - z);           // (1-t)^4 p^2 log2(1/(1-p)); ==0 at t==1
    B += bv;
    bool pos = (tt == 1.0f);
    A   += pos ? a : 0.0f;
    cnt += pos ? 1.0f : 0.0f;
}

__global__ __launch_bounds__(256, 4) void focal_kernel(
    const float* __restrict__ t_tl, const float* __restrict__ t_br,
    const float* __restrict__ x_tl, const float* __restrict__ x_br,
    float* __restrict__ ws)
{
    const int m = blockIdx.z;
    const int b = blockIdx.y;
    const float4* __restrict__ T4 = (const float4*)((m ? t_br : t_tl) + (size_t)b * N1);
    const float4* __restrict__ X4 = (const float4*)((m ? x_br : x_tl) + (size_t)b * N1);

    // thread's two positions per j-step; j-stride covers whole (b,m) plane
    const int JS = FB2 * 512;                       // 32768 float4 per j-step
    int p0 = blockIdx.x * 512 + threadIdx.x;        // pos 0
    // pos 1 = p0 + 256

    // register double-buffer: prefetch next (t,x) pair-of-pairs while computing
    float4 ct0 = T4[p0];
    float4 cx0 = X4[p0];
    float4 ct1 = T4[p0 + 256];
    float4 cx1 = X4[p0 + 256];

    float A = 0.0f, B = 0.0f, cnt = 0.0f;
    #pragma unroll
    for (int j = 0; j < NJ; ++j) {
        float4 nt0, nx0, nt1, nx1;
        if (j + 1 < NJ) {
            const int q = p0 + (j + 1) * JS;
            nt0 = T4[q];
            nx0 = X4[q];
            nt1 = T4[q + 256];
            nx1 = X4[q + 256];
        }
        #pragma unroll
        for (int c = 0; c < 4; ++c) proc((&ct0.x)[c], (&cx0.x)[c], A, B, cnt);
        #pragma unroll
        for (int c = 0; c < 4; ++c) proc((&ct1.x)[c], (&cx1.x)[c], A, B, cnt);
        ct0 = nt0; cx0 = nx0; ct1 = nt1; cx1 = nx1;
    }

    #pragma unroll
    for (int off = 32; off > 0; off >>= 1) {
        A   += __shfl_down(A  , off, 64);
        B   += __shfl_down(B  , off, 64);
        cnt += __shfl_down(cnt, off, 64);
    }
    __shared__ float red[3][4];
    const int lane = threadIdx.x & 63, wv = threadIdx.x >> 6;
    if (lane == 0) { red[0][wv] = A; red[1][wv] = B; red[2][wv] = cnt; }
    __syncthreads();
    if (threadIdx.x == 0) {
        atomicAdd(&ws[m*48 +  0 + b], red[0][0] + red[0][1] + red[0][2] + red[0][3]);
        atomicAdd(&ws[m*48 + 16 + b], red[1][0] + red[1][1] + red[1][2] + red[1][3]);
        atomicAdd(&ws[m*48 + 32 + b], red[2][0] + red[2][1] + red[2][2] + red[2][3]);
    }
}

// off-loss + triplet fused: one block per batch, KK=128 threads (2 waves)
__global__ void small_kernel(
    const float* __restrict__ to_tl, const float* __restrict__ to_br,
    const float* __restrict__ po_tl, const float* __restrict__ po_br,
    const float* __restrict__ e_tl,  const float* __restrict__ e_br,
    const int* __restrict__ idx_tl,  const int* __restrict__ idx_br,
    const int* __restrict__ mask,    float* __restrict__ ws)
{
    const int b = blockIdx.x, k = threadIdx.x;
    const int lane = threadIdx.x & 63, wv = threadIdx.x >> 6;

    float mf = (float)mask[b*KK + k];
    const int itl = idx_tl[b*KK + k];
    const int ibr = idx_br[b*KK + k];

    // ---- offset loss partials ----
    float s_tl = 0.0f, s_br = 0.0f;
    #pragma unroll
    for (int ch = 0; ch < 2; ++ch) {
        float pv = po_tl[((size_t)b*2 + ch)*HW + itl];
        float tv = to_tl[(b*KK + k)*2 + ch];
        float d = pv - tv, ad = fabsf(d);
        s_tl += (ad < 1.0f) ? 0.5f*d*d : (ad - 0.5f);
        pv = po_br[((size_t)b*2 + ch)*HW + ibr];
        tv = to_br[(b*KK + k)*2 + ch];
        d = pv - tv; ad = fabsf(d);
        s_br += (ad < 1.0f) ? 0.5f*d*d : (ad - 0.5f);
    }
    s_tl *= mf; s_br *= mf;

    // ---- triplet setup ----
    __shared__ float ek_s[KK], mf_s[KK], nred[2];
    float tl = e_tl[(size_t)b*HW + itl];
    float br = e_br[(size_t)b*HW + ibr];
    float ek = 0.5f * (tl + br);
    ek_s[k] = ek; mf_s[k] = mf;

    float nm = mf;
    #pragma unroll
    for (int off = 32; off > 0; off >>= 1) nm += __shfl_down(nm, off, 64);
    if (lane == 0) nred[wv] = nm;
    __syncthreads();
    const float num  = nred[0] + nred[1];
    const float inv  = 1.0f / (num + FEPS);
    const float num2 = (num - 1.0f) * num;
    const float inv2 = 1.0f / (num2 + FEPS);

    float pull = ((tl-ek)*(tl-ek) + (br-ek)*(br-ek)) * inv * mf;

    float push = 0.0f;
    if (mf == 1.0f) {
        for (int j = 0; j < KK; ++j) {
            if (mf_s[j] == 1.0f) {
                float d = fabsf(ek_s[j] - ek);
                push += (fmaxf(2.0f - d, 0.0f) - 2.0f * inv) * inv2;
            }
        }
    }

    #pragma unroll
    for (int off = 32; off > 0; off >>= 1) {
        s_tl += __shfl_down(s_tl, off, 64);
        s_br += __shfl_down(s_br, off, 64);
        mf   += __shfl_down(mf  , off, 64);
        pull += __shfl_down(pull, off, 64);
        push += __shfl_down(push, off, 64);
    }
    __shared__ float r[5][2];
    if (lane == 0) {
        r[0][wv] = s_tl; r[1][wv] = s_br; r[2][wv] = mf;
        r[3][wv] = pull; r[4][wv] = push;
    }
    __syncthreads();
    if (threadIdx.x == 0) {
        atomicAdd(&ws[96],  r[0][0] + r[0][1]);
        atomicAdd(&ws[97],  r[1][0] + r[1][1]);
        atomicAdd(&ws[98],  r[2][0] + r[2][1]);
        atomicAdd(&ws[99],  r[3][0] + r[3][1]);
        atomicAdd(&ws[100], r[4][0] + r[4][1]);
    }
}

__global__ void fin_kernel(const float* __restrict__ ws, float* __restrict__ out)
{
    if (threadIdx.x == 0 && blockIdx.x == 0) {
        const float NLN2 = -0.6931471805599453f;
        float det = 0.0f;
        for (int m = 0; m < 2; ++m) {
            float f = 0.0f;
            for (int b = 0; b < BB; ++b) {
                float pos = NLN2 * ws[m*48 +  0 + b];
                float neg = NLN2 * ws[m*48 + 16 + b];
                float n   = ws[m*48 + 32 + b];
                float per = (n == 0.0f) ? neg : (pos + neg) / n;
                f -= per;
            }
            det += 0.5f * f;
        }
        float numoff = ws[98] * 2.0f;
        float off = ws[96] / (numoff + FEPS) + ws[97] / (numoff + FEPS);
        out[0] = (det + ws[99] + ws[100] + off) / (float)BB;
    }
}

extern "C" void kernel_launch(void* const* d_in, const int* in_sizes, int n_in,
                              void* d_out, int out_size, void* d_ws, size_t ws_size,
                              hipStream_t stream) {
    const float* t_tl  = (const float*)d_in[0];
    const float* t_br  = (const float*)d_in[1];
    const float* to_tl = (const float*)d_in[2];
    const float* to_br = (const float*)d_in[3];
    const float* x_tl  = (const float*)d_in[4];
    const float* x_br  = (const float*)d_in[5];
    const float* po_tl = (const float*)d_in[6];
    const float* po_br = (const float*)d_in[7];
    const float* e_tl  = (const float*)d_in[8];
    const float* e_br  = (const float*)d_in[9];
    const int* idx_tl  = (const int*)d_in[10];
    const int* idx_br  = (const int*)d_in[11];
    const int* mask    = (const int*)d_in[12];
    float* ws = (float*)d_ws;

    hipMemsetAsync(ws, 0, 512, stream);
    focal_kernel<<<dim3(FB2, BB, 2), 256, 0, stream>>>(t_tl, t_br, x_tl, x_br, ws);
    small_kernel<<<BB, KK, 0, stream>>>(to_tl, to_br, po_tl, po_br, e_tl, e_br,
                                        idx_tl, idx_br, mask, ws);
    fin_kernel  <<<1, 64, 0, stream>>>(ws, (float*)d_out);
}